// Round 18
// baseline (1005.135 us; speedup 1.0000x reference)
//
#include <hip/hip_runtime.h>

#define N_NODES 50000
#define N_EDGES 600000
#define H 128
#define NODE_ELEMS (N_NODES * H)

typedef __bf16 bf16x8 __attribute__((ext_vector_type(8)));
typedef float f32x4 __attribute__((ext_vector_type(4)));
typedef unsigned short u16;
typedef u16 u16x8 __attribute__((ext_vector_type(8)));
typedef u16 u16x4 __attribute__((ext_vector_type(4)));

// d_ws layout (bytes):
//   wt: 11 matrices [128][128] bf16, wt[n][kslot]
//     0:E_W1a 1:E_W1b 2:E_W1c 3:E_W2 4:E_W3 5:E_W4 6:N_W1a 7:N_W1b 8:N_W2 9:N_W3 10:N_W4
//   mats 3,4,5,8,9,10 use k-PERMUTED rows (perm note below)
//   XA/XB/XN: bf16, SLOT-ordered per row (R7/R12/R13-proven, absmax 0.031)
//   agg: NPART stacked f32 copies (XCD-partition experiment, R18) — NPART
//   chosen at runtime from ws_size (8 -> 4 -> 1; 1 == R17 proven behavior).
// NUMERICS RULE (R8..R16): only the scalar "out2 = ea[] + ne" epilogue lands
// in the 0.031 absmax basin; in-register ov fusion / bf16 ne raises absmax to
// 0.09-0.13 and the post-timing re-check then fails. Edge path is untouched
// here; agg partition only changes f32 summation order (negligible).
#define MW 16384
#define WT_BYTES (11 * MW * 2)
#define XA_OFF WT_BYTES
#define NODE_B (N_NODES * H * 2)
#define XB_OFF (XA_OFF + NODE_B)
#define XN_OFF (XB_OFF + NODE_B)
#define AGG_OFF (XN_OFF + NODE_B)

__device__ inline u16 f2bf(float f) { return __builtin_bit_cast(u16, (__bf16)f); }
__device__ inline float bf2f(u16 u) {
  unsigned v = (unsigned)u << 16;
  return __builtin_bit_cast(float, v);
}

__device__ inline u16x8 cvt8(const float* __restrict__ p) {
  const float4 f0 = ((const float4*)p)[0];
  const float4 f1 = ((const float4*)p)[1];
  u16x8 o;
  o[0] = f2bf(f0.x); o[1] = f2bf(f0.y); o[2] = f2bf(f0.z); o[3] = f2bf(f0.w);
  o[4] = f2bf(f1.x); o[5] = f2bf(f1.y); o[6] = f2bf(f1.z); o[7] = f2bf(f1.w);
  return o;
}

// sum NPART stacked agg copies (f32), then single bf16 quantize — same
// rounding structure as the NPART=1 atomic-sum path.
template<int NPART>
__device__ inline u16x8 cvt8sum(const float* __restrict__ p) {
  float4 f0 = ((const float4*)p)[0];
  float4 f1 = ((const float4*)p)[1];
#pragma unroll
  for (int q = 1; q < NPART; ++q) {
    const float* pp = p + (size_t)q * NODE_ELEMS;
    const float4 a0 = ((const float4*)pp)[0];
    const float4 a1 = ((const float4*)pp)[1];
    f0.x += a0.x; f0.y += a0.y; f0.z += a0.z; f0.w += a0.w;
    f1.x += a1.x; f1.y += a1.y; f1.z += a1.z; f1.w += a1.w;
  }
  u16x8 o;
  o[0] = f2bf(f0.x); o[1] = f2bf(f0.y); o[2] = f2bf(f0.z); o[3] = f2bf(f0.w);
  o[4] = f2bf(f1.x); o[5] = f2bf(f1.y); o[6] = f2bf(f1.z); o[7] = f2bf(f1.w);
  return o;
}

__device__ inline f32x4 mfma_(u16x8 a, u16x8 b, f32x4 c) {
  return __builtin_amdgcn_mfma_f32_16x16x32_bf16(
      __builtin_bit_cast(bf16x8, a), __builtin_bit_cast(bf16x8, b), c, 0, 0, 0);
}

// Swapped-operand scheme (mfma(A=wt, B=data)):
//   B-frag lane(la,kg): data[row=la][feature kslot=k0*32+kg*8+j]
//   A-frag lane(la,kg): wt[(m*16+la)*128 + kslot]
//   D lane(la,kg): acc[m][r] = out[feature m*16+kg*4+r][row la]
// Repack D->next B (k-perm folded into wt of layers 2..4):
//   slot(k0,kg,j) <-> feature (k0*2+(j>>2))*16 + kg*4 + (j&3)

__global__ __launch_bounds__(256) void prep_weights(
    const float* __restrict__ ew1, const float* __restrict__ ew2,
    const float* __restrict__ ew3, const float* __restrict__ ew4,
    const float* __restrict__ nw1, const float* __restrict__ nw2,
    const float* __restrict__ nw3, const float* __restrict__ nw4,
    u16* __restrict__ wt)
{
  const int gid = blockIdx.x * 256 + threadIdx.x;
  if (gid >= 11 * MW) return;
  const int mat = gid >> 14, idx = gid & (MW - 1);
  const int n = idx >> 7, k = idx & 127;
  const float* src; int ro = 0; bool perm = false;
  switch (mat) {
    case 0: src = ew1; ro = 0;   break;
    case 1: src = ew1; ro = 128; break;
    case 2: src = ew1; ro = 256; break;
    case 3: src = ew2; perm = true; break;
    case 4: src = ew3; perm = true; break;
    case 5: src = ew4; perm = true; break;
    case 6: src = nw1; ro = 0;   break;
    case 7: src = nw1; ro = 128; break;
    case 8: src = nw2; perm = true; break;
    case 9: src = nw3; perm = true; break;
    default: src = nw4; perm = true; break;
  }
  int kk = k;
  if (perm) {
    const int k0 = k >> 5, kgg = (k >> 3) & 3, j = k & 7;
    kk = (k0 * 2 + (j >> 2)) * 16 + kgg * 4 + (j & 3);
  }
  wt[gid] = f2bf(src[(ro + kk) * H + n]);
}

// one layer, NT data tiles share each wt fragment
template<int NT>
__device__ inline void layerT(const u16* __restrict__ wm,
                              const u16x8 (&bfr)[NT][4],
                              const int la, const int kg,
                              f32x4 (&acc)[NT][8])
{
#pragma unroll
  for (int t = 0; t < NT; ++t)
#pragma unroll
    for (int m = 0; m < 8; ++m) acc[t][m] = {0.f, 0.f, 0.f, 0.f};
#pragma unroll
  for (int k0 = 0; k0 < 4; ++k0) {
#pragma unroll
    for (int m = 0; m < 8; ++m) {
      const u16x8 wf = *(const u16x8*)(wm + (m * 16 + la) * 128 + k0 * 32 + kg * 8);
#pragma unroll
      for (int t = 0; t < NT; ++t)
        acc[t][m] = mfma_(wf, bfr[t][k0], acc[t][m]);
    }
  }
}

// register repack D-spread -> next-layer B-frag, +bias +relu
template<int NT>
__device__ inline void packT(const f32x4 (&acc)[NT][8],
                             const float* __restrict__ bias,
                             const int kg, u16x8 (&bfr)[NT][4])
{
#pragma unroll
  for (int k0 = 0; k0 < 4; ++k0) {
    const f32x4 bA = *(const f32x4*)(bias + (k0 * 2) * 16 + kg * 4);
    const f32x4 bB = *(const f32x4*)(bias + (k0 * 2 + 1) * 16 + kg * 4);
#pragma unroll
    for (int t = 0; t < NT; ++t) {
      u16x8 o;
#pragma unroll
      for (int j = 0; j < 8; ++j) {
        const int m = k0 * 2 + (j >> 2), r = j & 3;
        float v = acc[t][m][r] + ((j >> 2) ? bB[r] : bA[r]);
        v = v > 0.f ? v : 0.f;
        o[j] = f2bf(v);
      }
      bfr[t][k0] = o;
    }
  }
}

// XA/XB/XN: x @ {E_W1a, E_W1b, N_W1a}, stored bf16 in SLOT (permuted) layout
__global__ __launch_bounds__(256) void precompute(
    const float* __restrict__ x, const u16* __restrict__ wt,
    u16* __restrict__ xa, u16* __restrict__ xb, u16* __restrict__ xn)
{
  const int tid = threadIdx.x;
  const int lane = tid & 63, w = tid >> 6;
  const int n0 = blockIdx.x * 64 + w * 16;
  const int la = lane & 15, kg = lane >> 4;
  const int row = n0 + la < N_NODES ? n0 + la : N_NODES - 1;

  u16x8 bfx[1][4];
#pragma unroll
  for (int k0 = 0; k0 < 4; ++k0)
    bfx[0][k0] = cvt8(x + (size_t)row * H + k0 * 32 + kg * 8);

  const int mats[3] = {0, 1, 6};
  u16* outs[3] = {xa, xb, xn};
#pragma unroll
  for (int m3 = 0; m3 < 3; ++m3) {
    f32x4 acc[1][8];
    layerT<1>(wt + mats[m3] * MW, bfx, la, kg, acc);
    if (n0 + la < N_NODES) {
      u16* out = outs[m3] + (size_t)(n0 + la) * H;
#pragma unroll
      for (int m = 0; m < 8; ++m) {
        u16x4 o;
#pragma unroll
        for (int r = 0; r < 4; ++r) o[r] = f2bf(acc[0][m][r]);
        *(u16x4*)(out + (m >> 1) * 32 + kg * 8 + (m & 1) * 4) = o;
      }
    }
  }
}

template<int NPART>
__global__ __launch_bounds__(256, 4) void edge_kernel(
    const float* __restrict__ ea, const int* __restrict__ eidx,
    const u16* __restrict__ wt,
    const u16* __restrict__ xag, const u16* __restrict__ xbg,
    const float* __restrict__ b1, const float* __restrict__ b2,
    const float* __restrict__ b3, const float* __restrict__ b4,
    const float* __restrict__ g, const float* __restrict__ be,
    float* __restrict__ out2, float* __restrict__ agg)
{
  __shared__ float sT[4][1024];   // per-wave [16][64] f32 tile, 16KB/block
  const int tid = threadIdx.x;
  const int lane = tid & 63, w = tid >> 6;
  const int e0 = blockIdx.x * 128 + w * 32;
  const int la = lane & 15, kg = lane >> 4;
  const int* __restrict__ snd = eidx;
  const int* __restrict__ rcv = eidx + N_EDGES;
  char* tileB = (char*)sT[w];
  // XCD-partitioned agg copy: round-robin dispatch puts blocks with equal
  // (bid & NPART-1) on the same XCD (m157 heuristic) -> atomic lines stay in
  // one (NPART=8) or two (NPART=4) L2s instead of migrating across all 8.
  float* __restrict__ aggP =
      agg + (size_t)(blockIdx.x & (NPART - 1)) * NODE_ELEMS;

  int rA[2];
  rA[0] = e0 + la;      if (rA[0] >= N_EDGES) rA[0] = N_EDGES - 1;
  rA[1] = e0 + 16 + la; if (rA[1] >= N_EDGES) rA[1] = N_EDGES - 1;
  size_t sbH[2], rbH[2];
#pragma unroll
  for (int t = 0; t < 2; ++t) {
    sbH[t] = (size_t)snd[rA[t]] * H;
    rbH[t] = (size_t)rcv[rA[t]] * H;
  }

  // B-frags of ea (natural slot order)
  u16x8 bfr[2][4];
#pragma unroll
  for (int t = 0; t < 2; ++t)
#pragma unroll
    for (int k0 = 0; k0 < 4; ++k0)
      bfr[t][k0] = cvt8(ea + (size_t)rA[t] * H + k0 * 32 + kg * 8);

  // L1c: S = ea @ W1c (swapped)
  f32x4 acc[2][8];
  layerT<2>(wt + 2 * MW, bfr, la, kg, acc);

  // gathers (slot layout matches D-spread repack)
  u16x8 xa[2][4], xb[2][4];
#pragma unroll
  for (int t = 0; t < 2; ++t)
#pragma unroll
    for (int k0 = 0; k0 < 4; ++k0) {
      xa[t][k0] = *(const u16x8*)(xag + sbH[t] + k0 * 32 + kg * 8);
      xb[t][k0] = *(const u16x8*)(xbg + rbH[t] + k0 * 32 + kg * 8);
    }

  // h1 = relu(S + b1 + XA + XB): pure-register repack
#pragma unroll
  for (int k0 = 0; k0 < 4; ++k0) {
    const f32x4 bA = *(const f32x4*)(b1 + (k0 * 2) * 16 + kg * 4);
    const f32x4 bB = *(const f32x4*)(b1 + (k0 * 2 + 1) * 16 + kg * 4);
#pragma unroll
    for (int t = 0; t < 2; ++t) {
      u16x8 o;
#pragma unroll
      for (int j = 0; j < 8; ++j) {
        const int m = k0 * 2 + (j >> 2), r = j & 3;
        float v = acc[t][m][r] + ((j >> 2) ? bB[r] : bA[r]) +
                  bf2f(xa[t][k0][j]) + bf2f(xb[t][k0][j]);
        v = v > 0.f ? v : 0.f;
        o[j] = f2bf(v);
      }
      bfr[t][k0] = o;
    }
  }

  // layers 2..4 (permuted wt)
  layerT<2>(wt + 3 * MW, bfr, la, kg, acc);
  packT<2>(acc, b2, kg, bfr);
  layerT<2>(wt + 4 * MW, bfr, la, kg, acc);
  packT<2>(acc, b3, kg, bfr);
  layerT<2>(wt + 5 * MW, bfr, la, kg, acc);

  // bias4 + LN stats (lane owns row la; reduce across 4 kg-lanes)
  float vs[2] = {0.f, 0.f}, vq[2] = {0.f, 0.f};
#pragma unroll
  for (int m = 0; m < 8; ++m) {
    const f32x4 b4m = *(const f32x4*)(b4 + m * 16 + kg * 4);
#pragma unroll
    for (int t = 0; t < 2; ++t)
#pragma unroll
      for (int r = 0; r < 4; ++r) {
        const float v = acc[t][m][r] + b4m[r];
        acc[t][m][r] = v;
        vs[t] += v; vq[t] += v * v;
      }
  }
#pragma unroll
  for (int t = 0; t < 2; ++t) {
    vs[t] += __shfl_xor(vs[t], 16, 64);
    vq[t] += __shfl_xor(vq[t], 16, 64);
    vs[t] += __shfl_xor(vs[t], 32, 64);
    vq[t] += __shfl_xor(vq[t], 32, 64);
  }

  // ---- epilogue: two-phase [16][64] f32 LDS transpose (R13-proven) ----
  // tile: row pitch 256B; off(row, bc) = row*256 + (bc ^ ((row&7)<<4)).
  // Write: f32x4, 2-way max banks. Read: scalar, conflict-free.
  // Per atomic/store INSTRUCTION: col = h*64+n*16+la -> one contiguous 64B
  // line (R12 rule: stride-16B lanes cost 2x coherence write-back).
#pragma unroll
  for (int t = 0; t < 2; ++t) {
    const float mean = vs[t] * (1.0f / 128.0f);
    const float var = vq[t] * (1.0f / 128.0f) - mean * mean;
    const float rstd = rsqrtf(var + 1e-5f);
#pragma unroll
    for (int h = 0; h < 2; ++h) {
      // write half: features [h*64, h*64+64), lane's own row la
#pragma unroll
      for (int mm = 0; mm < 4; ++mm) {
        const int m = h * 4 + mm;
        const int co = m * 16 + kg * 4;
        const f32x4 gm = *(const f32x4*)(g + co);
        const f32x4 bem = *(const f32x4*)(be + co);
        f32x4 nv;
#pragma unroll
        for (int r = 0; r < 4; ++r)
          nv[r] = (acc[t][m][r] - mean) * rstd * gm[r] + bem[r];
        *(f32x4*)(tileB + la * 256 + ((mm * 64 + kg * 16) ^ ((la & 7) << 4))) = nv;
      }
      asm volatile("" ::: "memory");   // order DS write phase before read phase

      // read transposed: lane covers rows kg*4+rr, col h*64 + n*16 + la
#pragma unroll
      for (int rr = 0; rr < 4; ++rr) {
        const int trow = kg * 4 + rr;
        const int rowg = e0 + t * 16 + trow;
        if (rowg < N_EDGES) {
          const int rv = rcv[rowg];
          const size_t rb = (size_t)rowg * H;
          float* aggr = aggP + (size_t)rv * H;
#pragma unroll
          for (int n = 0; n < 4; ++n) {
            const int col = h * 64 + n * 16 + la;
            const int bc = n * 64 + la * 4;
            const float ne = *(const float*)(tileB + trow * 256 + (bc ^ ((trow & 7) << 4)));
            out2[rb + col] = ea[rb + col] + ne;
            atomicAdd(aggr + col, ne);
          }
        }
      }
      asm volatile("" ::: "memory");   // order reads before next phase's writes (WAR)
    }
  }
}

template<int NPART>
__global__ __launch_bounds__(256, 4) void node_kernel(
    const float* __restrict__ x, const float* __restrict__ agg,
    const u16* __restrict__ wt, const u16* __restrict__ xng,
    const float* __restrict__ b1, const float* __restrict__ b2,
    const float* __restrict__ b3, const float* __restrict__ b4,
    const float* __restrict__ g, const float* __restrict__ be,
    float* __restrict__ out1)
{
  const int tid = threadIdx.x;
  const int lane = tid & 63, w = tid >> 6;
  const int n0 = blockIdx.x * 64 + w * 16;
  const int la = lane & 15, kg = lane >> 4;
  const int row = n0 + la < N_NODES ? n0 + la : N_NODES - 1;

  u16x8 bfr[1][4];
#pragma unroll
  for (int k0 = 0; k0 < 4; ++k0)
    bfr[0][k0] = cvt8sum<NPART>(agg + (size_t)row * H + k0 * 32 + kg * 8);
  u16x8 xn[4];
#pragma unroll
  for (int k0 = 0; k0 < 4; ++k0)
    xn[k0] = *(const u16x8*)(xng + (size_t)row * H + k0 * 32 + kg * 8);

  // L1b: S = agg @ N_W1b (natural k)
  f32x4 acc[1][8];
  layerT<1>(wt + 7 * MW, bfr, la, kg, acc);

  // h1 = relu(S + b1 + XN)
#pragma unroll
  for (int k0 = 0; k0 < 4; ++k0) {
    const f32x4 bA = *(const f32x4*)(b1 + (k0 * 2) * 16 + kg * 4);
    const f32x4 bB = *(const f32x4*)(b1 + (k0 * 2 + 1) * 16 + kg * 4);
    u16x8 o;
#pragma unroll
    for (int j = 0; j < 8; ++j) {
      const int m = k0 * 2 + (j >> 2), r = j & 3;
      float v = acc[0][m][r] + ((j >> 2) ? bB[r] : bA[r]) + bf2f(xn[k0][j]);
      v = v > 0.f ? v : 0.f;
      o[j] = f2bf(v);
    }
    bfr[0][k0] = o;
  }

  layerT<1>(wt + 8 * MW, bfr, la, kg, acc);
  packT<1>(acc, b2, kg, bfr);
  layerT<1>(wt + 9 * MW, bfr, la, kg, acc);
  packT<1>(acc, b3, kg, bfr);
  layerT<1>(wt + 10 * MW, bfr, la, kg, acc);

  float vs = 0.f, vq = 0.f;
#pragma unroll
  for (int m = 0; m < 8; ++m) {
    const f32x4 b4m = *(const f32x4*)(b4 + m * 16 + kg * 4);
#pragma unroll
    for (int r = 0; r < 4; ++r) {
      const float v = acc[0][m][r] + b4m[r];
      acc[0][m][r] = v;
      vs += v; vq += v * v;
    }
  }
  vs += __shfl_xor(vs, 16, 64);
  vq += __shfl_xor(vq, 16, 64);
  vs += __shfl_xor(vs, 32, 64);
  vq += __shfl_xor(vq, 32, 64);

  if (n0 + la < N_NODES) {
    const float mean = vs * (1.0f / 128.0f);
    const float var = vq * (1.0f / 128.0f) - mean * mean;
    const float rstd = rsqrtf(var + 1e-5f);
    const size_t rb = (size_t)(n0 + la) * H;
#pragma unroll
    for (int m = 0; m < 8; ++m) {
      const int co = m * 16 + kg * 4;
      const f32x4 gm = *(const f32x4*)(g + co);
      const f32x4 bem = *(const f32x4*)(be + co);
      const f32x4 xv = *(const f32x4*)(x + rb + co);
      f32x4 ov;
#pragma unroll
      for (int r = 0; r < 4; ++r)
        ov[r] = xv[r] + (acc[0][m][r] - mean) * rstd * gm[r] + bem[r];
      *(f32x4*)(out1 + rb + co) = ov;
    }
  }
}

extern "C" void kernel_launch(void* const* d_in, const int* in_sizes, int n_in,
                              void* d_out, int out_size, void* d_ws, size_t ws_size,
                              hipStream_t stream) {
  const float* x   = (const float*)d_in[0];
  const float* ea  = (const float*)d_in[1];
  const int*   ei  = (const int*)d_in[2];
  const float* ew1 = (const float*)d_in[3];
  const float* eb1 = (const float*)d_in[4];
  const float* ew2 = (const float*)d_in[5];
  const float* eb2 = (const float*)d_in[6];
  const float* ew3 = (const float*)d_in[7];
  const float* eb3 = (const float*)d_in[8];
  const float* ew4 = (const float*)d_in[9];
  const float* eb4 = (const float*)d_in[10];
  const float* eg  = (const float*)d_in[11];
  const float* ebe = (const float*)d_in[12];
  const float* nw1 = (const float*)d_in[13];
  const float* nb1 = (const float*)d_in[14];
  const float* nw2 = (const float*)d_in[15];
  const float* nb2 = (const float*)d_in[16];
  const float* nw3 = (const float*)d_in[17];
  const float* nb3 = (const float*)d_in[18];
  const float* nw4 = (const float*)d_in[19];
  const float* nb4 = (const float*)d_in[20];
  const float* ng  = (const float*)d_in[21];
  const float* nbe = (const float*)d_in[22];

  char* ws = (char*)d_ws;
  u16* wt = (u16*)ws;
  u16* xa = (u16*)(ws + XA_OFF);
  u16* xb = (u16*)(ws + XB_OFF);
  u16* xn = (u16*)(ws + XN_OFF);
  float* agg = (float*)(ws + AGG_OFF);
  float* out1 = (float*)d_out;
  float* out2 = out1 + (size_t)N_NODES * H;

  prep_weights<<<(11 * MW + 255) / 256, 256, 0, stream>>>(
      ew1, ew2, ew3, ew4, nw1, nw2, nw3, nw4, wt);
  precompute<<<(N_NODES + 63) / 64, 256, 0, stream>>>(x, wt, xa, xb, xn);

  const size_t need8 = (size_t)AGG_OFF + 8ull * NODE_ELEMS * 4;
  const size_t need4 = (size_t)AGG_OFF + 4ull * NODE_ELEMS * 4;
  if (ws_size >= need8) {
    hipMemsetAsync(agg, 0, 8ull * NODE_ELEMS * 4, stream);
    edge_kernel<8><<<(N_EDGES + 127) / 128, 256, 0, stream>>>(
        ea, ei, wt, xa, xb, eb1, eb2, eb3, eb4, eg, ebe, out2, agg);
    node_kernel<8><<<(N_NODES + 63) / 64, 256, 0, stream>>>(
        x, agg, wt, xn, nb1, nb2, nb3, nb4, ng, nbe, out1);
  } else if (ws_size >= need4) {
    hipMemsetAsync(agg, 0, 4ull * NODE_ELEMS * 4, stream);
    edge_kernel<4><<<(N_EDGES + 127) / 128, 256, 0, stream>>>(
        ea, ei, wt, xa, xb, eb1, eb2, eb3, eb4, eg, ebe, out2, agg);
    node_kernel<4><<<(N_NODES + 63) / 64, 256, 0, stream>>>(
        x, agg, wt, xn, nb1, nb2, nb3, nb4, ng, nbe, out1);
  } else {
    hipMemsetAsync(agg, 0, (size_t)NODE_ELEMS * 4, stream);
    edge_kernel<1><<<(N_EDGES + 127) / 128, 256, 0, stream>>>(
        ea, ei, wt, xa, xb, eb1, eb2, eb3, eb4, eg, ebe, out2, agg);
    node_kernel<1><<<(N_NODES + 63) / 64, 256, 0, stream>>>(
        x, agg, wt, xn, nb1, nb2, nb3, nb4, ng, nbe, out1);
  }
}

// Round 19
// 713.176 us; speedup vs baseline: 1.4094x; 1.4094x over previous
//
#include <hip/hip_runtime.h>

#define N_NODES 50000
#define N_EDGES 600000
#define H 128
#define NODE_ELEMS (N_NODES * H)

typedef __bf16 bf16x8 __attribute__((ext_vector_type(8)));
typedef float f32x4 __attribute__((ext_vector_type(4)));
typedef unsigned short u16;
typedef unsigned int u32;
typedef u16 u16x8 __attribute__((ext_vector_type(8)));
typedef u16 u16x4 __attribute__((ext_vector_type(4)));

// d_ws layout (bytes):
//   wt: 11 matrices [128][128] bf16, wt[n][kslot]
//     0:E_W1a 1:E_W1b 2:E_W1c 3:E_W2 4:E_W3 5:E_W4 6:N_W1a 7:N_W1b 8:N_W2 9:N_W3 10:N_W4
//   mats 3,4,5,8,9,10 use k-PERMUTED rows (perm note below)
//   XA/XB/XN: bf16, SLOT-ordered per row (R7/R12/R13-proven, absmax 0.031)
//   agg: bf16 (R19): halves agg row to 256B -> halves random atomic
//   line-touches (R18 showed edge time == hbm_bytes / 1.9TB/s pattern-BW).
// NUMERICS RULE (R8..R16): only the scalar "out2 = ea[] + ne" f32 epilogue
// lands in the 0.031 basin for output 1 — that path is byte-identical to R17
// here. bf16 agg only perturbs output 0 (node), historically drift-free.
#define MW 16384
#define WT_BYTES (11 * MW * 2)
#define XA_OFF WT_BYTES
#define NODE_B (N_NODES * H * 2)
#define XB_OFF (XA_OFF + NODE_B)
#define XN_OFF (XB_OFF + NODE_B)
#define AGG_OFF (XN_OFF + NODE_B)          // bf16 agg, 12.8 MB

__device__ inline u16 f2bf(float f) { return __builtin_bit_cast(u16, (__bf16)f); }
__device__ inline float bf2f(u16 u) {
  unsigned v = (unsigned)u << 16;
  return __builtin_bit_cast(float, v);
}

__device__ inline u16x8 cvt8(const float* __restrict__ p) {
  const float4 f0 = ((const float4*)p)[0];
  const float4 f1 = ((const float4*)p)[1];
  u16x8 o;
  o[0] = f2bf(f0.x); o[1] = f2bf(f0.y); o[2] = f2bf(f0.z); o[3] = f2bf(f0.w);
  o[4] = f2bf(f1.x); o[5] = f2bf(f1.y); o[6] = f2bf(f1.z); o[7] = f2bf(f1.w);
  return o;
}

__device__ inline f32x4 mfma_(u16x8 a, u16x8 b, f32x4 c) {
  return __builtin_amdgcn_mfma_f32_16x16x32_bf16(
      __builtin_bit_cast(bf16x8, a), __builtin_bit_cast(bf16x8, b), c, 0, 0, 0);
}

// Swapped-operand scheme (mfma(A=wt, B=data)):
//   B-frag lane(la,kg): data[row=la][feature kslot=k0*32+kg*8+j]
//   A-frag lane(la,kg): wt[(m*16+la)*128 + kslot]
//   D lane(la,kg): acc[m][r] = out[feature m*16+kg*4+r][row la]
// Repack D->next B (k-perm folded into wt of layers 2..4):
//   slot(k0,kg,j) <-> feature (k0*2+(j>>2))*16 + kg*4 + (j&3)

__global__ __launch_bounds__(256) void prep_weights(
    const float* __restrict__ ew1, const float* __restrict__ ew2,
    const float* __restrict__ ew3, const float* __restrict__ ew4,
    const float* __restrict__ nw1, const float* __restrict__ nw2,
    const float* __restrict__ nw3, const float* __restrict__ nw4,
    u16* __restrict__ wt)
{
  const int gid = blockIdx.x * 256 + threadIdx.x;
  if (gid >= 11 * MW) return;
  const int mat = gid >> 14, idx = gid & (MW - 1);
  const int n = idx >> 7, k = idx & 127;
  const float* src; int ro = 0; bool perm = false;
  switch (mat) {
    case 0: src = ew1; ro = 0;   break;
    case 1: src = ew1; ro = 128; break;
    case 2: src = ew1; ro = 256; break;
    case 3: src = ew2; perm = true; break;
    case 4: src = ew3; perm = true; break;
    case 5: src = ew4; perm = true; break;
    case 6: src = nw1; ro = 0;   break;
    case 7: src = nw1; ro = 128; break;
    case 8: src = nw2; perm = true; break;
    case 9: src = nw3; perm = true; break;
    default: src = nw4; perm = true; break;
  }
  int kk = k;
  if (perm) {
    const int k0 = k >> 5, kgg = (k >> 3) & 3, j = k & 7;
    kk = (k0 * 2 + (j >> 2)) * 16 + kgg * 4 + (j & 3);
  }
  wt[gid] = f2bf(src[(ro + kk) * H + n]);
}

// one layer, NT data tiles share each wt fragment
template<int NT>
__device__ inline void layerT(const u16* __restrict__ wm,
                              const u16x8 (&bfr)[NT][4],
                              const int la, const int kg,
                              f32x4 (&acc)[NT][8])
{
#pragma unroll
  for (int t = 0; t < NT; ++t)
#pragma unroll
    for (int m = 0; m < 8; ++m) acc[t][m] = {0.f, 0.f, 0.f, 0.f};
#pragma unroll
  for (int k0 = 0; k0 < 4; ++k0) {
#pragma unroll
    for (int m = 0; m < 8; ++m) {
      const u16x8 wf = *(const u16x8*)(wm + (m * 16 + la) * 128 + k0 * 32 + kg * 8);
#pragma unroll
      for (int t = 0; t < NT; ++t)
        acc[t][m] = mfma_(wf, bfr[t][k0], acc[t][m]);
    }
  }
}

// register repack D-spread -> next-layer B-frag, +bias +relu
template<int NT>
__device__ inline void packT(const f32x4 (&acc)[NT][8],
                             const float* __restrict__ bias,
                             const int kg, u16x8 (&bfr)[NT][4])
{
#pragma unroll
  for (int k0 = 0; k0 < 4; ++k0) {
    const f32x4 bA = *(const f32x4*)(bias + (k0 * 2) * 16 + kg * 4);
    const f32x4 bB = *(const f32x4*)(bias + (k0 * 2 + 1) * 16 + kg * 4);
#pragma unroll
    for (int t = 0; t < NT; ++t) {
      u16x8 o;
#pragma unroll
      for (int j = 0; j < 8; ++j) {
        const int m = k0 * 2 + (j >> 2), r = j & 3;
        float v = acc[t][m][r] + ((j >> 2) ? bB[r] : bA[r]);
        v = v > 0.f ? v : 0.f;
        o[j] = f2bf(v);
      }
      bfr[t][k0] = o;
    }
  }
}

// XA/XB/XN: x @ {E_W1a, E_W1b, N_W1a}, stored bf16 in SLOT (permuted) layout
__global__ __launch_bounds__(256) void precompute(
    const float* __restrict__ x, const u16* __restrict__ wt,
    u16* __restrict__ xa, u16* __restrict__ xb, u16* __restrict__ xn)
{
  const int tid = threadIdx.x;
  const int lane = tid & 63, w = tid >> 6;
  const int n0 = blockIdx.x * 64 + w * 16;
  const int la = lane & 15, kg = lane >> 4;
  const int row = n0 + la < N_NODES ? n0 + la : N_NODES - 1;

  u16x8 bfx[1][4];
#pragma unroll
  for (int k0 = 0; k0 < 4; ++k0)
    bfx[0][k0] = cvt8(x + (size_t)row * H + k0 * 32 + kg * 8);

  const int mats[3] = {0, 1, 6};
  u16* outs[3] = {xa, xb, xn};
#pragma unroll
  for (int m3 = 0; m3 < 3; ++m3) {
    f32x4 acc[1][8];
    layerT<1>(wt + mats[m3] * MW, bfx, la, kg, acc);
    if (n0 + la < N_NODES) {
      u16* out = outs[m3] + (size_t)(n0 + la) * H;
#pragma unroll
      for (int m = 0; m < 8; ++m) {
        u16x4 o;
#pragma unroll
        for (int r = 0; r < 4; ++r) o[r] = f2bf(acc[0][m][r]);
        *(u16x4*)(out + (m >> 1) * 32 + kg * 8 + (m & 1) * 4) = o;
      }
    }
  }
}

__global__ __launch_bounds__(256, 4) void edge_kernel(
    const float* __restrict__ ea, const int* __restrict__ eidx,
    const u16* __restrict__ wt,
    const u16* __restrict__ xag, const u16* __restrict__ xbg,
    const float* __restrict__ b1, const float* __restrict__ b2,
    const float* __restrict__ b3, const float* __restrict__ b4,
    const float* __restrict__ g, const float* __restrict__ be,
    float* __restrict__ out2, u16* __restrict__ aggb)
{
  __shared__ float sT[4][1024];   // per-wave [16][64] f32 tile, 16KB/block
  const int tid = threadIdx.x;
  const int lane = tid & 63, w = tid >> 6;
  const int e0 = blockIdx.x * 128 + w * 32;
  const int la = lane & 15, kg = lane >> 4;
  const int* __restrict__ snd = eidx;
  const int* __restrict__ rcv = eidx + N_EDGES;
  char* tileB = (char*)sT[w];

  int rA[2];
  rA[0] = e0 + la;      if (rA[0] >= N_EDGES) rA[0] = N_EDGES - 1;
  rA[1] = e0 + 16 + la; if (rA[1] >= N_EDGES) rA[1] = N_EDGES - 1;
  size_t sbH[2], rbH[2];
#pragma unroll
  for (int t = 0; t < 2; ++t) {
    sbH[t] = (size_t)snd[rA[t]] * H;
    rbH[t] = (size_t)rcv[rA[t]] * H;
  }

  // B-frags of ea (natural slot order)
  u16x8 bfr[2][4];
#pragma unroll
  for (int t = 0; t < 2; ++t)
#pragma unroll
    for (int k0 = 0; k0 < 4; ++k0)
      bfr[t][k0] = cvt8(ea + (size_t)rA[t] * H + k0 * 32 + kg * 8);

  // L1c: S = ea @ W1c (swapped)
  f32x4 acc[2][8];
  layerT<2>(wt + 2 * MW, bfr, la, kg, acc);

  // gathers (slot layout matches D-spread repack)
  u16x8 xa[2][4], xb[2][4];
#pragma unroll
  for (int t = 0; t < 2; ++t)
#pragma unroll
    for (int k0 = 0; k0 < 4; ++k0) {
      xa[t][k0] = *(const u16x8*)(xag + sbH[t] + k0 * 32 + kg * 8);
      xb[t][k0] = *(const u16x8*)(xbg + rbH[t] + k0 * 32 + kg * 8);
    }

  // h1 = relu(S + b1 + XA + XB): pure-register repack
#pragma unroll
  for (int k0 = 0; k0 < 4; ++k0) {
    const f32x4 bA = *(const f32x4*)(b1 + (k0 * 2) * 16 + kg * 4);
    const f32x4 bB = *(const f32x4*)(b1 + (k0 * 2 + 1) * 16 + kg * 4);
#pragma unroll
    for (int t = 0; t < 2; ++t) {
      u16x8 o;
#pragma unroll
      for (int j = 0; j < 8; ++j) {
        const int m = k0 * 2 + (j >> 2), r = j & 3;
        float v = acc[t][m][r] + ((j >> 2) ? bB[r] : bA[r]) +
                  bf2f(xa[t][k0][j]) + bf2f(xb[t][k0][j]);
        v = v > 0.f ? v : 0.f;
        o[j] = f2bf(v);
      }
      bfr[t][k0] = o;
    }
  }

  // layers 2..4 (permuted wt)
  layerT<2>(wt + 3 * MW, bfr, la, kg, acc);
  packT<2>(acc, b2, kg, bfr);
  layerT<2>(wt + 4 * MW, bfr, la, kg, acc);
  packT<2>(acc, b3, kg, bfr);
  layerT<2>(wt + 5 * MW, bfr, la, kg, acc);

  // bias4 + LN stats (lane owns row la; reduce across 4 kg-lanes)
  float vs[2] = {0.f, 0.f}, vq[2] = {0.f, 0.f};
#pragma unroll
  for (int m = 0; m < 8; ++m) {
    const f32x4 b4m = *(const f32x4*)(b4 + m * 16 + kg * 4);
#pragma unroll
    for (int t = 0; t < 2; ++t)
#pragma unroll
      for (int r = 0; r < 4; ++r) {
        const float v = acc[t][m][r] + b4m[r];
        acc[t][m][r] = v;
        vs[t] += v; vq[t] += v * v;
      }
  }
#pragma unroll
  for (int t = 0; t < 2; ++t) {
    vs[t] += __shfl_xor(vs[t], 16, 64);
    vq[t] += __shfl_xor(vq[t], 16, 64);
    vs[t] += __shfl_xor(vs[t], 32, 64);
    vq[t] += __shfl_xor(vq[t], 32, 64);
  }

  // ---- epilogue: two-phase [16][64] f32 LDS transpose (R13-proven) ----
  // tile: row pitch 256B; off(row, bc) = row*256 + (bc ^ ((row&7)<<4)).
  // out2 path byte-identical to R17 (0.031 basin). Atomics: pk_add_bf16,
  // 2 bf16/op; per instruction 16 lanes x 4B = one contiguous 64B line.
#pragma unroll
  for (int t = 0; t < 2; ++t) {
    const float mean = vs[t] * (1.0f / 128.0f);
    const float var = vq[t] * (1.0f / 128.0f) - mean * mean;
    const float rstd = rsqrtf(var + 1e-5f);
#pragma unroll
    for (int h = 0; h < 2; ++h) {
      // write half: features [h*64, h*64+64), lane's own row la
#pragma unroll
      for (int mm = 0; mm < 4; ++mm) {
        const int m = h * 4 + mm;
        const int co = m * 16 + kg * 4;
        const f32x4 gm = *(const f32x4*)(g + co);
        const f32x4 bem = *(const f32x4*)(be + co);
        f32x4 nv;
#pragma unroll
        for (int r = 0; r < 4; ++r)
          nv[r] = (acc[t][m][r] - mean) * rstd * gm[r] + bem[r];
        *(f32x4*)(tileB + la * 256 + ((mm * 64 + kg * 16) ^ ((la & 7) << 4))) = nv;
      }
      asm volatile("" ::: "memory");   // order DS write phase before read phase

      // read transposed: lane covers rows kg*4+rr
#pragma unroll
      for (int rr = 0; rr < 4; ++rr) {
        const int trow = kg * 4 + rr;
        const int rowg = e0 + t * 16 + trow;
        if (rowg < N_EDGES) {
          const int rv = rcv[rowg];
          const size_t rb = (size_t)rowg * H;
          // out2: col n*16+la (R17-identical, 64B/line/instr)
#pragma unroll
          for (int n = 0; n < 4; ++n) {
            const int col = h * 64 + n * 16 + la;
            const int bc = n * 64 + la * 4;
            const float ne = *(const float*)(tileB + trow * 256 + (bc ^ ((trow & 7) << 4)));
            out2[rb + col] = ea[rb + col] + ne;
          }
          // agg scatter: packed bf16, lane owns cols {2la, 2la+1} of a
          // 32-col group; 16 lanes x 4B = 64B contiguous per instruction.
#pragma unroll
          for (int n2 = 0; n2 < 2; ++n2) {
            const int bcp = n2 * 128 + la * 8;
            const float2 nep = *(const float2*)(tileB + trow * 256 +
                                                (bcp ^ ((trow & 7) << 4)));
            const u32 pk = (u32)f2bf(nep.x) | ((u32)f2bf(nep.y) << 16);
            u16* ap = aggb + (size_t)rv * H + h * 64 + n2 * 32 + la * 2;
            asm volatile("global_atomic_pk_add_bf16 %0, %1, off"
                         :: "v"(ap), "v"(pk) : "memory");
          }
        }
      }
      asm volatile("" ::: "memory");   // order reads before next phase's writes (WAR)
    }
  }
}

__global__ __launch_bounds__(256, 4) void node_kernel(
    const float* __restrict__ x, const u16* __restrict__ aggb,
    const u16* __restrict__ wt, const u16* __restrict__ xng,
    const float* __restrict__ b1, const float* __restrict__ b2,
    const float* __restrict__ b3, const float* __restrict__ b4,
    const float* __restrict__ g, const float* __restrict__ be,
    float* __restrict__ out1)
{
  const int tid = threadIdx.x;
  const int lane = tid & 63, w = tid >> 6;
  const int n0 = blockIdx.x * 64 + w * 16;
  const int la = lane & 15, kg = lane >> 4;
  const int row = n0 + la < N_NODES ? n0 + la : N_NODES - 1;

  // agg already bf16 in natural feature order -> direct B-frag loads
  u16x8 bfr[1][4];
#pragma unroll
  for (int k0 = 0; k0 < 4; ++k0)
    bfr[0][k0] = *(const u16x8*)(aggb + (size_t)row * H + k0 * 32 + kg * 8);
  u16x8 xn[4];
#pragma unroll
  for (int k0 = 0; k0 < 4; ++k0)
    xn[k0] = *(const u16x8*)(xng + (size_t)row * H + k0 * 32 + kg * 8);

  // L1b: S = agg @ N_W1b (natural k)
  f32x4 acc[1][8];
  layerT<1>(wt + 7 * MW, bfr, la, kg, acc);

  // h1 = relu(S + b1 + XN)
#pragma unroll
  for (int k0 = 0; k0 < 4; ++k0) {
    const f32x4 bA = *(const f32x4*)(b1 + (k0 * 2) * 16 + kg * 4);
    const f32x4 bB = *(const f32x4*)(b1 + (k0 * 2 + 1) * 16 + kg * 4);
    u16x8 o;
#pragma unroll
    for (int j = 0; j < 8; ++j) {
      const int m = k0 * 2 + (j >> 2), r = j & 3;
      float v = acc[0][m][r] + ((j >> 2) ? bB[r] : bA[r]) + bf2f(xn[k0][j]);
      v = v > 0.f ? v : 0.f;
      o[j] = f2bf(v);
    }
    bfr[0][k0] = o;
  }

  layerT<1>(wt + 8 * MW, bfr, la, kg, acc);
  packT<1>(acc, b2, kg, bfr);
  layerT<1>(wt + 9 * MW, bfr, la, kg, acc);
  packT<1>(acc, b3, kg, bfr);
  layerT<1>(wt + 10 * MW, bfr, la, kg, acc);

  float vs = 0.f, vq = 0.f;
#pragma unroll
  for (int m = 0; m < 8; ++m) {
    const f32x4 b4m = *(const f32x4*)(b4 + m * 16 + kg * 4);
#pragma unroll
    for (int r = 0; r < 4; ++r) {
      const float v = acc[0][m][r] + b4m[r];
      acc[0][m][r] = v;
      vs += v; vq += v * v;
    }
  }
  vs += __shfl_xor(vs, 16, 64);
  vq += __shfl_xor(vq, 16, 64);
  vs += __shfl_xor(vs, 32, 64);
  vq += __shfl_xor(vq, 32, 64);

  if (n0 + la < N_NODES) {
    const float mean = vs * (1.0f / 128.0f);
    const float var = vq * (1.0f / 128.0f) - mean * mean;
    const float rstd = rsqrtf(var + 1e-5f);
    const size_t rb = (size_t)(n0 + la) * H;
#pragma unroll
    for (int m = 0; m < 8; ++m) {
      const int co = m * 16 + kg * 4;
      const f32x4 gm = *(const f32x4*)(g + co);
      const f32x4 bem = *(const f32x4*)(be + co);
      const f32x4 xv = *(const f32x4*)(x + rb + co);
      f32x4 ov;
#pragma unroll
      for (int r = 0; r < 4; ++r)
        ov[r] = xv[r] + (acc[0][m][r] - mean) * rstd * gm[r] + bem[r];
      *(f32x4*)(out1 + rb + co) = ov;
    }
  }
}

extern "C" void kernel_launch(void* const* d_in, const int* in_sizes, int n_in,
                              void* d_out, int out_size, void* d_ws, size_t ws_size,
                              hipStream_t stream) {
  const float* x   = (const float*)d_in[0];
  const float* ea  = (const float*)d_in[1];
  const int*   ei  = (const int*)d_in[2];
  const float* ew1 = (const float*)d_in[3];
  const float* eb1 = (const float*)d_in[4];
  const float* ew2 = (const float*)d_in[5];
  const float* eb2 = (const float*)d_in[6];
  const float* ew3 = (const float*)d_in[7];
  const float* eb3 = (const float*)d_in[8];
  const float* ew4 = (const float*)d_in[9];
  const float* eb4 = (const float*)d_in[10];
  const float* eg  = (const float*)d_in[11];
  const float* ebe = (const float*)d_in[12];
  const float* nw1 = (const float*)d_in[13];
  const float* nb1 = (const float*)d_in[14];
  const float* nw2 = (const float*)d_in[15];
  const float* nb2 = (const float*)d_in[16];
  const float* nw3 = (const float*)d_in[17];
  const float* nb3 = (const float*)d_in[18];
  const float* nw4 = (const float*)d_in[19];
  const float* nb4 = (const float*)d_in[20];
  const float* ng  = (const float*)d_in[21];
  const float* nbe = (const float*)d_in[22];

  char* ws = (char*)d_ws;
  u16* wt = (u16*)ws;
  u16* xa = (u16*)(ws + XA_OFF);
  u16* xb = (u16*)(ws + XB_OFF);
  u16* xn = (u16*)(ws + XN_OFF);
  u16* aggb = (u16*)(ws + AGG_OFF);
  float* out1 = (float*)d_out;
  float* out2 = out1 + (size_t)N_NODES * H;

  hipMemsetAsync(aggb, 0, (size_t)NODE_ELEMS * 2, stream);
  prep_weights<<<(11 * MW + 255) / 256, 256, 0, stream>>>(
      ew1, ew2, ew3, ew4, nw1, nw2, nw3, nw4, wt);
  precompute<<<(N_NODES + 63) / 64, 256, 0, stream>>>(x, wt, xa, xb, xn);
  edge_kernel<<<(N_EDGES + 127) / 128, 256, 0, stream>>>(
      ea, ei, wt, xa, xb, eb1, eb2, eb3, eb4, eg, ebe, out2, aggb);
  node_kernel<<<(N_NODES + 63) / 64, 256, 0, stream>>>(
      x, aggb, wt, xn, nb1, nb2, nb3, nb4, ng, nbe, out1);
}